// Round 8
// baseline (187.208 us; speedup 1.0000x reference)
//
#include <hip/hip_runtime.h>

typedef unsigned int u32;
typedef unsigned short u16;
typedef unsigned long long u64;

#define NTOK 4096
#define DDIM 512
#define NEXP 8
#define HDIM 1024

typedef __attribute__((ext_vector_type(8))) __bf16 bf16x8;
typedef __attribute__((ext_vector_type(4))) float f32x4;

typedef const void __attribute__((address_space(1))) as1_cvoid;
typedef void __attribute__((address_space(3))) as3_void;

__device__ __forceinline__ float b2f(u16 u) {
    union { u32 i; float f; } v; v.i = ((u32)u) << 16; return v.f;
}
__device__ __forceinline__ u16 f2b(float f) {
    u32 x = __builtin_bit_cast(u32, f);
    x += 0x7fffu + ((x >> 16) & 1u);
    return (u16)(x >> 16);
}

// width-16 direct global->LDS. LDS dest is wave-uniform base + lane*16
// (linear); swizzle lives in the per-lane GLOBAL source address (rule 21).
__device__ __forceinline__ void gl16(const u16* g, u16* l) {
    __builtin_amdgcn_global_load_lds((as1_cvoid*)g, (as3_void*)l, 16, 0, 0);
}

// REGRESSION LEDGER (settled, do not retry):
//  r1: per-token atomicAdd on counts[8] -> 8192 serialized RMWs on one line
//      across 8 XCDs, ~100us. Lists must be built without hot-line atomics.
//  r3: cooperative grid.sync() ~75us/sync on gfx950 (XCD L2 flush). Dead end.
//  r4: fusing combine into fc2 via scattered f32 atomicAdd (+16us net).
//      Epilogues stay bulk coalesced; scatter lives in its own pass.
//  r6: consumer-split conversion = neutral. r7: expert<->XCD pin = neutral
//      (kept, free). Launch plumbing + cache placement exhausted; r8 attacks
//      tile intensity: fc2 was 2.67 MFMA/KB staged (vs fc1's 4.0) -> 128x128.

#define XN   ((size_t)NTOK * DDIM)            // 2,097,152
#define W1N  ((size_t)NEXP * 2 * HDIM * DDIM) // 8,388,608
#define B1N  ((size_t)NEXP * 2 * HDIM)        // 16,384
#define W2N  ((size_t)NEXP * DDIM * HDIM)     // 4,194,304
#define B2N  ((size_t)NEXP * DDIM)            // 4,096

#define ROUTER_BLOCKS (NTOK / 4)                          // 1024
#define CONVA_BLOCKS  ((int)((XN + W1N + B1N) / 8 / 256)) // 5128 exact
#define CONVB_BLOCKS  ((int)((W2N + B2N) / 8 / 256))      // 2050 exact
#define FC1_BLOCKS    (NEXP * (NTOK / 128) * (HDIM / 64))  // 4096
#define FC2_BLOCKS    (NEXP * (NTOK / 128) * (DDIM / 128)) // 1024

__device__ __forceinline__ void convert8(const float* __restrict__ src,
                                         u16* __restrict__ dst, size_t off) {
    const float4 a = *(const float4*)(src + off);
    const float4 b = *(const float4*)(src + off + 4);
    union { u16 t[8]; uint4 v; } u;
    u.t[0] = f2b(a.x); u.t[1] = f2b(a.y); u.t[2] = f2b(a.z); u.t[3] = f2b(a.w);
    u.t[4] = f2b(b.x); u.t[5] = f2b(b.y); u.t[6] = f2b(b.z); u.t[7] = f2b(b.w);
    *(uint4*)(dst + off) = u.v;
}

// ---------------- K1: router + convert(x, fc1_w, fc1_b) ----------------
__global__ __launch_bounds__(256) void router_conva_kernel(
    const float* __restrict__ x, const float* __restrict__ rw, const float* __restrict__ rb,
    const float* __restrict__ w1, const float* __restrict__ b1,
    u16* __restrict__ xb, u16* __restrict__ w1b, u16* __restrict__ b1b,
    u16* __restrict__ tok_epack, float* __restrict__ tok_w)
{
    const int tid = threadIdx.x;
    const int bid = (int)blockIdx.x;

    if (bid >= ROUTER_BLOCKS) {
        const size_t i = ((size_t)(bid - ROUTER_BLOCKS) * 256 + tid) * 8;
        if (i < XN)            convert8(x,  xb,  i);
        else if (i < XN + W1N) convert8(w1, w1b, i - XN);
        else                   convert8(b1, b1b, i - XN - W1N);
        return;
    }

    // ---- router: one wave per token ----
    const int lane = tid & 63;
    const int t = bid * 4 + (tid >> 6);

    const float4* p = (const float4*)(x + (size_t)t * DDIM + lane * 8);
    const float4 xa = p[0], xc = p[1];
    float xf[8] = { xa.x, xa.y, xa.z, xa.w, xc.x, xc.y, xc.z, xc.w };

    float acc[NEXP];
#pragma unroll
    for (int e = 0; e < NEXP; e++) {
        const float4* q = (const float4*)(rw + e * DDIM + lane * 8);
        const float4 wa = q[0], wb = q[1];
        acc[e] = xf[0] * wa.x + xf[1] * wa.y + xf[2] * wa.z + xf[3] * wa.w
               + xf[4] * wb.x + xf[5] * wb.y + xf[6] * wb.z + xf[7] * wb.w;
    }
#pragma unroll
    for (int off = 32; off > 0; off >>= 1) {
#pragma unroll
        for (int e = 0; e < NEXP; e++) acc[e] += __shfl_xor(acc[e], off, 64);
    }
    if (lane == 0) {
#pragma unroll
        for (int e = 0; e < NEXP; e++) acc[e] += rb[e];
        // top-2, lowest-index tie-break (matches lax.top_k)
        int e0 = 0;
#pragma unroll
        for (int e = 1; e < NEXP; e++) if (acc[e] > acc[e0]) e0 = e;
        int e1 = -1;
#pragma unroll
        for (int e = 0; e < NEXP; e++) {
            if (e == e0) continue;
            if (e1 < 0 || acc[e] > acc[e1]) e1 = e;
        }
        const float w1v = 1.f / (1.f + __expf(acc[e0] - acc[e1]));
        tok_epack[t] = (u16)((u32)e0 | ((u32)e1 << 8));
        tok_w[t * 2] = 1.f - w1v;
        tok_w[t * 2 + 1] = w1v;
    }
}

// ---------------- K2: build lists (single block, ballot compaction) ----------------
// list entry packs token | slot<<15 so fc2 writes y in token-slot order and
// combine needs no indirection.
__global__ __launch_bounds__(256) void build_kernel(
    const u16* __restrict__ tok_epack,
    u32* __restrict__ counts, u32* __restrict__ offsets,
    u16* __restrict__ list)
{
    const int tid = threadIdx.x;
    __shared__ u32 eLDS[NTOK / 2 + NEXP];
    u32* cLDS = eLDS + NTOK / 2;
    for (int i = tid; i < NTOK / 2; i += 256) eLDS[i] = ((const u32*)tok_epack)[i];
    __syncthreads();
    const int wave = tid >> 6, lane = tid & 63;
    const u64 ltmask = ((u64)1 << lane) - 1;
#pragma unroll
    for (int pass = 0; pass < 2; pass++) {
        const u32 e = (u32)(wave + pass * 4);
        u32 r = 0;
        for (int c = 0; c < 64; c++) {
            const int t = c * 64 + lane;
            const u32 pair = eLDS[t >> 1];
            const u32 p = (pair >> ((t & 1) * 16)) & 0xFFFFu;
            const u32 e0 = p & 0xFFu, e1v = (p >> 8) & 0xFFu;
            const u64 m0 = __ballot(e0 == e);
            if (e0 == e) {
                const u32 idx = r + (u32)__popcll(m0 & ltmask);
                list[e * NTOK + idx] = (u16)t;              // slot 0
            }
            r += (u32)__popcll(m0);
            const u64 m1 = __ballot(e1v == e);
            if (e1v == e) {
                const u32 idx = r + (u32)__popcll(m1 & ltmask);
                list[e * NTOK + idx] = (u16)(t | 0x8000u);  // slot 1
            }
            r += (u32)__popcll(m1);
        }
        if (lane == 0) cLDS[e] = r;
    }
    __syncthreads();
    if (tid == 0) {
        u32 o = 0;
        for (int i = 0; i < NEXP; i++) { counts[i] = cLDS[i]; offsets[i] = o; o += cLDS[i]; }
    }
}

// ---------------- K3: fc1 + SwiGLU (r2-verified body) + piggybacked w2/b2 conversion ----------------
__global__ __launch_bounds__(256, 3) void fc1_swiglu_kernel(
    const u16* __restrict__ xb, const u16* __restrict__ w1b, const u16* __restrict__ b1b,
    const float* __restrict__ w2, const float* __restrict__ b2,
    u16* __restrict__ w2b, u16* __restrict__ b2b,
    const u32* __restrict__ counts, const u32* __restrict__ offsets,
    const u16* __restrict__ list, u16* __restrict__ a_packed)
{
    const int tid = threadIdx.x;
    const int bid = (int)blockIdx.x;

    if (bid >= FC1_BLOCKS) {
        const size_t i = ((size_t)(bid - FC1_BLOCKS) * 256 + tid) * 8;
        if (i < W2N) convert8(w2, w2b, i);
        else         convert8(b2, b2b, i - W2N);
        return;
    }

    const int e   = bid & 7;            // XCD pin (round-robin bid%8)
    const int idx = bid >> 3;
    const int n0   = (idx & 15) * 64;   // x fastest: A-panel reuse on-XCD
    const int row0 = (idx >> 4) * 128;
    const int cnt = (int)counts[e];
    if (row0 >= cnt) return;

    __shared__ u16 As[128 * 64], B1s[64 * 64], B2s[64 * 64];

    const int wave = tid >> 6, lane = tid & 63;
    const int mrow0 = (wave >> 1) * 64;
    const int ncol0 = (wave & 1) * 32;
    const int mm = lane & 15;
    const int qb = lane >> 4;
    const int msw = mm & 7;

    const u16 *srcA[4], *srcB1[2], *srcB2[2];
    u16 *dstA[4], *dstB1[2], *dstB2[2];
    const int lrow8 = lane >> 3;
    const int colOff = ((lane & 7) ^ lrow8) << 3;   // element offset (bf16)
#pragma unroll
    for (int j = 0; j < 4; j++) {               // A: 32 rows per wave
        int r = row0 + wave * 32 + j * 8 + lrow8;
        if (r >= cnt) r = cnt - 1;
        const int tok = (int)(list[e * NTOK + r] & 0xFFFu);
        srcA[j] = xb + (size_t)tok * DDIM + colOff;
        dstA[j] = &As[(wave * 32 + j * 8) * 64];
    }
#pragma unroll
    for (int j = 0; j < 2; j++) {               // B1/B2: 16 rows per wave
        const int n = n0 + wave * 16 + j * 8 + lrow8;
        srcB1[j] = w1b + ((size_t)e * 2 * HDIM + n) * DDIM + colOff;
        srcB2[j] = w1b + ((size_t)e * 2 * HDIM + HDIM + n) * DDIM + colOff;
        dstB1[j] = &B1s[(wave * 16 + j * 8) * 64];
        dstB2[j] = &B2s[(wave * 16 + j * 8) * 64];
    }

    f32x4 acc1[4][2], acc2[4][2];
#pragma unroll
    for (int mt = 0; mt < 4; mt++)
#pragma unroll
        for (int nt = 0; nt < 2; nt++) {
            acc1[mt][nt] = f32x4{0, 0, 0, 0};
            acc2[mt][nt] = f32x4{0, 0, 0, 0};
        }

    for (int k0 = 0; k0 < DDIM; k0 += 64) {
        __syncthreads();
#pragma unroll
        for (int j = 0; j < 4; j++) gl16(srcA[j] + k0, dstA[j]);
#pragma unroll
        for (int j = 0; j < 2; j++) gl16(srcB1[j] + k0, dstB1[j]);
#pragma unroll
        for (int j = 0; j < 2; j++) gl16(srcB2[j] + k0, dstB2[j]);
        __syncthreads();   // drains vmcnt(0) before s_barrier
#pragma unroll
        for (int kk = 0; kk < 2; kk++) {
            const int g = kk * 4 + qb;
            bf16x8 af[4];
#pragma unroll
            for (int mt = 0; mt < 4; mt++)
                af[mt] = *(const bf16x8*)(&As[(mrow0 + mt * 16 + mm) * 64 + ((g ^ msw) << 3)]);
#pragma unroll
            for (int nt = 0; nt < 2; nt++) {
                const bf16x8 b1f = *(const bf16x8*)(&B1s[(ncol0 + nt * 16 + mm) * 64 + ((g ^ msw) << 3)]);
                const bf16x8 b2f = *(const bf16x8*)(&B2s[(ncol0 + nt * 16 + mm) * 64 + ((g ^ msw) << 3)]);
#pragma unroll
                for (int mt = 0; mt < 4; mt++) {
                    acc1[mt][nt] = __builtin_amdgcn_mfma_f32_16x16x32_bf16(af[mt], b1f, acc1[mt][nt], 0, 0, 0);
                    acc2[mt][nt] = __builtin_amdgcn_mfma_f32_16x16x32_bf16(af[mt], b2f, acc2[mt][nt], 0, 0, 0);
                }
            }
        }
    }

    const u32 obase = offsets[e];
    const int rbv = qb * 4;
#pragma unroll
    for (int nt = 0; nt < 2; nt++) {
        const int n = n0 + ncol0 + nt * 16 + mm;
        const float bb1 = b2f(b1b[(size_t)e * 2 * HDIM + n]);
        const float bb2 = b2f(b1b[(size_t)e * 2 * HDIM + HDIM + n]);
#pragma unroll
        for (int mt = 0; mt < 4; mt++) {
#pragma unroll
            for (int r = 0; r < 4; r++) {
                const int gr = row0 + mrow0 + mt * 16 + rbv + r;
                if (gr < cnt) {
                    const float h1 = acc1[mt][nt][r] + bb1;
                    const float h2 = acc2[mt][nt][r] + bb2;
                    const float av = h1 / (1.f + __expf(-h1)) * h2;
                    a_packed[(size_t)(obase + (u32)gr) * HDIM + n] = f2b(av);
                }
            }
        }
    }
}

// ---------------- K4: fc2, 128x128 tile (r8: intensity 2.67 -> 4.0 MFMA/KB) ----------------
// N widened 64->128: a_packed re-read factor halves (8->4 d-tiles), active
// blocks ~256 = one residency round at 3/CU. Single-buffered 32KB LDS
// (dbuf+128-tile = 64KB -> 2/CU, the m132 regression — avoided).
// acc[4][4] = 64 VGPR accumulator, fits 170-VGPR budget at (256,3).
__global__ __launch_bounds__(256, 3) void fc2_kernel(
    const u16* __restrict__ a_packed, const u16* __restrict__ w2b, const u16* __restrict__ b2b,
    const u32* __restrict__ counts, const u32* __restrict__ offsets,
    const u16* __restrict__ list, u16* __restrict__ y_tok)
{
    const int tid = threadIdx.x;
    const int bid = (int)blockIdx.x;
    const int e   = bid & 7;            // XCD pin
    const int idx = bid >> 3;
    const int d0   = (idx & 3) * 128;   // x fastest: A-panel reuse on-XCD
    const int row0 = (idx >> 2) * 128;
    const int cnt = (int)counts[e];
    if (row0 >= cnt) return;
    const u32 obase = offsets[e];

    __shared__ u16 As[128 * 64], Bs[128 * 64];   // 16KB + 16KB

    const int wave = tid >> 6, lane = tid & 63;
    const int mrow0 = (wave >> 1) * 64;
    const int ncol0 = (wave & 1) * 64;
    const int mm = lane & 15;
    const int qb = lane >> 4;
    const int msw = mm & 7;

    const u16 *srcA[4], *srcB[4];
    u16 *dstA[4], *dstB[4];
    const int lrow8 = lane >> 3;
    const int colOff = ((lane & 7) ^ lrow8) << 3;
#pragma unroll
    for (int j = 0; j < 4; j++) {               // A: 32 rows per wave
        int r = row0 + wave * 32 + j * 8 + lrow8;
        if (r >= cnt) r = cnt - 1;
        srcA[j] = a_packed + (size_t)(obase + (u32)r) * HDIM + colOff;
        dstA[j] = &As[(wave * 32 + j * 8) * 64];
    }
#pragma unroll
    for (int j = 0; j < 4; j++) {               // B: 32 d-rows per wave
        const int d = d0 + wave * 32 + j * 8 + lrow8;
        srcB[j] = w2b + ((size_t)e * DDIM + d) * HDIM + colOff;
        dstB[j] = &Bs[(wave * 32 + j * 8) * 64];
    }

    f32x4 acc[4][4];
#pragma unroll
    for (int mt = 0; mt < 4; mt++)
#pragma unroll
        for (int nt = 0; nt < 4; nt++) acc[mt][nt] = f32x4{0, 0, 0, 0};

    for (int k0 = 0; k0 < HDIM; k0 += 64) {
        __syncthreads();
#pragma unroll
        for (int j = 0; j < 4; j++) gl16(srcA[j] + k0, dstA[j]);
#pragma unroll
        for (int j = 0; j < 4; j++) gl16(srcB[j] + k0, dstB[j]);
        __syncthreads();   // drains vmcnt(0) before s_barrier
#pragma unroll
        for (int kk = 0; kk < 2; kk++) {
            const int g = kk * 4 + qb;
            bf16x8 af[4];
#pragma unroll
            for (int mt = 0; mt < 4; mt++)
                af[mt] = *(const bf16x8*)(&As[(mrow0 + mt * 16 + mm) * 64 + ((g ^ msw) << 3)]);
#pragma unroll
            for (int nt = 0; nt < 4; nt++) {
                const bf16x8 bfv = *(const bf16x8*)(&Bs[(ncol0 + nt * 16 + mm) * 64 + ((g ^ msw) << 3)]);
#pragma unroll
                for (int mt = 0; mt < 4; mt++)
                    acc[mt][nt] = __builtin_amdgcn_mfma_f32_16x16x32_bf16(af[mt], bfv, acc[mt][nt], 0, 0, 0);
            }
        }
    }

    const int rbv = qb * 4;
#pragma unroll
    for (int nt = 0; nt < 4; nt++) {
        const int n = d0 + ncol0 + nt * 16 + mm;
        const float bb = b2f(b2b[(size_t)e * DDIM + n]);
#pragma unroll
        for (int mt = 0; mt < 4; mt++) {
#pragma unroll
            for (int r = 0; r < 4; r++) {
                const int gr = row0 + mrow0 + mt * 16 + rbv + r;
                if (gr < cnt) {
                    const u32 v = (u32)list[e * NTOK + gr];
                    const u32 row = ((v & 0xFFFu) << 1) | (v >> 15);   // 2*token + slot
                    y_tok[(size_t)row * DDIM + n] = f2b(acc[mt][nt][r] + bb);
                }
            }
        }
    }
}

// ---------------- K5: weighted combine (pure streaming, no indirection) ----------------
__global__ __launch_bounds__(256) void combine_kernel(
    const u16* __restrict__ y_tok, const float* __restrict__ tok_w,
    float* __restrict__ out)
{
    const int tid = threadIdx.x;
    const int lane = tid & 63;
    const int t = (int)blockIdx.x * 4 + (tid >> 6);
    const float w0 = tok_w[t * 2], w1 = tok_w[t * 2 + 1];

    const uint4 va = *(const uint4*)(y_tok + (size_t)(t * 2)     * DDIM + lane * 8);
    const uint4 vb = *(const uint4*)(y_tok + (size_t)(t * 2 + 1) * DDIM + lane * 8);
    const u16* ap = (const u16*)&va;
    const u16* bp = (const u16*)&vb;
    float r[8];
#pragma unroll
    for (int j = 0; j < 8; j++) r[j] = w0 * b2f(ap[j]) + w1 * b2f(bp[j]);

    float* op = out + (size_t)t * DDIM + lane * 8;
    *(float4*)op       = float4{r[0], r[1], r[2], r[3]};
    *(float4*)(op + 4) = float4{r[4], r[5], r[6], r[7]};
}

extern "C" void kernel_launch(void* const* d_in, const int* in_sizes, int n_in,
                              void* d_out, int out_size, void* d_ws, size_t ws_size,
                              hipStream_t stream)
{
    const float* x  = (const float*)d_in[0];
    const float* rw = (const float*)d_in[1];
    const float* rb = (const float*)d_in[2];
    const float* w1 = (const float*)d_in[3];
    const float* b1 = (const float*)d_in[4];
    const float* w2 = (const float*)d_in[5];
    const float* b2 = (const float*)d_in[6];
    float* outp = (float*)d_out;
    (void)in_sizes; (void)n_in; (void)out_size; (void)ws_size;

    char* ws = (char*)d_ws;
    size_t off = 0;
    auto take = [&](size_t bytes) -> char* {
        char* p = ws + off;
        off = (off + bytes + 255) & ~(size_t)255;
        return p;
    };
    u32* counts    = (u32*)take(NEXP * 4);
    u32* offsets   = (u32*)take(NEXP * 4);
    u16* list      = (u16*)take((size_t)NEXP * NTOK * 2);
    u16* tok_epack = (u16*)take((size_t)NTOK * 2);
    float* tok_w   = (float*)take((size_t)NTOK * 2 * 4);
    u16* a_packed  = (u16*)take((size_t)2 * NTOK * HDIM * 2);   // 16.8 MB
    u16* y_tok     = (u16*)take((size_t)2 * NTOK * DDIM * 2);   // 8.4 MB
    u16* xb  = (u16*)take(XN * 2);                              // 4.2 MB
    u16* w1b = (u16*)take(W1N * 2);                             // 16.8 MB
    u16* b1b = (u16*)take(B1N * 2);
    u16* w2b = (u16*)take(W2N * 2);                             // 8.4 MB
    u16* b2b = (u16*)take(B2N * 2);

    router_conva_kernel<<<ROUTER_BLOCKS + CONVA_BLOCKS, 256, 0, stream>>>(
        x, rw, rb, w1, b1, xb, w1b, b1b, tok_epack, tok_w);

    build_kernel<<<1, 256, 0, stream>>>(tok_epack, counts, offsets, list);

    fc1_swiglu_kernel<<<FC1_BLOCKS + CONVB_BLOCKS, 256, 0, stream>>>(
        xb, w1b, b1b, w2, b2, w2b, b2b, counts, offsets, list, a_packed);

    fc2_kernel<<<FC2_BLOCKS, 256, 0, stream>>>(
        a_packed, w2b, b2b, counts, offsets, list, y_tok);

    combine_kernel<<<NTOK / 4, 256, 0, stream>>>(y_tok, tok_w, outp);
}

// Round 9
// 178.376 us; speedup vs baseline: 1.0495x; 1.0495x over previous
//
#include <hip/hip_runtime.h>

typedef unsigned int u32;
typedef unsigned short u16;
typedef unsigned long long u64;

#define NTOK 4096
#define DDIM 512
#define NEXP 8
#define HDIM 1024

typedef __attribute__((ext_vector_type(8))) __bf16 bf16x8;
typedef __attribute__((ext_vector_type(4))) float f32x4;

typedef const void __attribute__((address_space(1))) as1_cvoid;
typedef void __attribute__((address_space(3))) as3_void;

__device__ __forceinline__ float b2f(u16 u) {
    union { u32 i; float f; } v; v.i = ((u32)u) << 16; return v.f;
}
__device__ __forceinline__ u16 f2b(float f) {
    u32 x = __builtin_bit_cast(u32, f);
    x += 0x7fffu + ((x >> 16) & 1u);
    return (u16)(x >> 16);
}

// width-16 direct global->LDS. LDS dest is wave-uniform base + lane*16
// (linear); swizzle lives in the per-lane GLOBAL source address (rule 21).
__device__ __forceinline__ void gl16(const u16* g, u16* l) {
    __builtin_amdgcn_global_load_lds((as1_cvoid*)g, (as3_void*)l, 16, 0, 0);
}

// REGRESSION LEDGER (settled, do not retry):
//  r1: per-token atomicAdd on counts[8] -> 8192 serialized RMWs on one line
//      across 8 XCDs, ~100us. Lists must be built without hot-line atomics.
//  r3: cooperative grid.sync() ~75us/sync on gfx950 (XCD L2 flush). Dead end.
//  r4: fusing combine into fc2 via scattered f32 atomicAdd (+16us net).
//      Epilogues stay bulk coalesced; scatter lives in its own pass.
//  r6: consumer-split conversion = neutral. r7: expert<->XCD pin = neutral
//      (kept, free).
//  r8: fc2 128x128 single-buffer = REGRESSION (+6us vs r7): intensity gain
//      cancelled by losing dbuf prefetch (exposed vmcnt(0) drains x16 steps).
//      fc2 stays dbuf 128x64. r9 single-variable test: fc1 (256,3)->(256,4).

#define XN   ((size_t)NTOK * DDIM)            // 2,097,152
#define W1N  ((size_t)NEXP * 2 * HDIM * DDIM) // 8,388,608
#define B1N  ((size_t)NEXP * 2 * HDIM)        // 16,384
#define W2N  ((size_t)NEXP * DDIM * HDIM)     // 4,194,304
#define B2N  ((size_t)NEXP * DDIM)            // 4,096

#define ROUTER_BLOCKS (NTOK / 4)                          // 1024
#define CONVA_BLOCKS  ((int)((XN + W1N + B1N) / 8 / 256)) // 5128 exact
#define CONVB_BLOCKS  ((int)((W2N + B2N) / 8 / 256))      // 2050 exact
#define FC1_BLOCKS    (NEXP * (NTOK / 128) * (HDIM / 64)) // 4096
#define FC2_BLOCKS    (NEXP * (NTOK / 128) * (DDIM / 64)) // 2048

__device__ __forceinline__ void convert8(const float* __restrict__ src,
                                         u16* __restrict__ dst, size_t off) {
    const float4 a = *(const float4*)(src + off);
    const float4 b = *(const float4*)(src + off + 4);
    union { u16 t[8]; uint4 v; } u;
    u.t[0] = f2b(a.x); u.t[1] = f2b(a.y); u.t[2] = f2b(a.z); u.t[3] = f2b(a.w);
    u.t[4] = f2b(b.x); u.t[5] = f2b(b.y); u.t[6] = f2b(b.z); u.t[7] = f2b(b.w);
    *(uint4*)(dst + off) = u.v;
}

// ---------------- K1: router + convert(x, fc1_w, fc1_b) ----------------
__global__ __launch_bounds__(256) void router_conva_kernel(
    const float* __restrict__ x, const float* __restrict__ rw, const float* __restrict__ rb,
    const float* __restrict__ w1, const float* __restrict__ b1,
    u16* __restrict__ xb, u16* __restrict__ w1b, u16* __restrict__ b1b,
    u16* __restrict__ tok_epack, float* __restrict__ tok_w)
{
    const int tid = threadIdx.x;
    const int bid = (int)blockIdx.x;

    if (bid >= ROUTER_BLOCKS) {
        const size_t i = ((size_t)(bid - ROUTER_BLOCKS) * 256 + tid) * 8;
        if (i < XN)            convert8(x,  xb,  i);
        else if (i < XN + W1N) convert8(w1, w1b, i - XN);
        else                   convert8(b1, b1b, i - XN - W1N);
        return;
    }

    // ---- router: one wave per token ----
    const int lane = tid & 63;
    const int t = bid * 4 + (tid >> 6);

    const float4* p = (const float4*)(x + (size_t)t * DDIM + lane * 8);
    const float4 xa = p[0], xc = p[1];
    float xf[8] = { xa.x, xa.y, xa.z, xa.w, xc.x, xc.y, xc.z, xc.w };

    float acc[NEXP];
#pragma unroll
    for (int e = 0; e < NEXP; e++) {
        const float4* q = (const float4*)(rw + e * DDIM + lane * 8);
        const float4 wa = q[0], wb = q[1];
        acc[e] = xf[0] * wa.x + xf[1] * wa.y + xf[2] * wa.z + xf[3] * wa.w
               + xf[4] * wb.x + xf[5] * wb.y + xf[6] * wb.z + xf[7] * wb.w;
    }
#pragma unroll
    for (int off = 32; off > 0; off >>= 1) {
#pragma unroll
        for (int e = 0; e < NEXP; e++) acc[e] += __shfl_xor(acc[e], off, 64);
    }
    if (lane == 0) {
#pragma unroll
        for (int e = 0; e < NEXP; e++) acc[e] += rb[e];
        // top-2, lowest-index tie-break (matches lax.top_k)
        int e0 = 0;
#pragma unroll
        for (int e = 1; e < NEXP; e++) if (acc[e] > acc[e0]) e0 = e;
        int e1 = -1;
#pragma unroll
        for (int e = 0; e < NEXP; e++) {
            if (e == e0) continue;
            if (e1 < 0 || acc[e] > acc[e1]) e1 = e;
        }
        const float w1v = 1.f / (1.f + __expf(acc[e0] - acc[e1]));
        tok_epack[t] = (u16)((u32)e0 | ((u32)e1 << 8));
        tok_w[t * 2] = 1.f - w1v;
        tok_w[t * 2 + 1] = w1v;
    }
}

// ---------------- K2: build lists (single block, ballot compaction) ----------------
// list entry packs token | slot<<15 so fc2 writes y in token-slot order and
// combine needs no indirection.
__global__ __launch_bounds__(256) void build_kernel(
    const u16* __restrict__ tok_epack,
    u32* __restrict__ counts, u32* __restrict__ offsets,
    u16* __restrict__ list)
{
    const int tid = threadIdx.x;
    __shared__ u32 eLDS[NTOK / 2 + NEXP];
    u32* cLDS = eLDS + NTOK / 2;
    for (int i = tid; i < NTOK / 2; i += 256) eLDS[i] = ((const u32*)tok_epack)[i];
    __syncthreads();
    const int wave = tid >> 6, lane = tid & 63;
    const u64 ltmask = ((u64)1 << lane) - 1;
#pragma unroll
    for (int pass = 0; pass < 2; pass++) {
        const u32 e = (u32)(wave + pass * 4);
        u32 r = 0;
        for (int c = 0; c < 64; c++) {
            const int t = c * 64 + lane;
            const u32 pair = eLDS[t >> 1];
            const u32 p = (pair >> ((t & 1) * 16)) & 0xFFFFu;
            const u32 e0 = p & 0xFFu, e1v = (p >> 8) & 0xFFu;
            const u64 m0 = __ballot(e0 == e);
            if (e0 == e) {
                const u32 idx = r + (u32)__popcll(m0 & ltmask);
                list[e * NTOK + idx] = (u16)t;              // slot 0
            }
            r += (u32)__popcll(m0);
            const u64 m1 = __ballot(e1v == e);
            if (e1v == e) {
                const u32 idx = r + (u32)__popcll(m1 & ltmask);
                list[e * NTOK + idx] = (u16)(t | 0x8000u);  // slot 1
            }
            r += (u32)__popcll(m1);
        }
        if (lane == 0) cLDS[e] = r;
    }
    __syncthreads();
    if (tid == 0) {
        u32 o = 0;
        for (int i = 0; i < NEXP; i++) { counts[i] = cLDS[i]; offsets[i] = o; o += cLDS[i]; }
    }
}

// ---------------- K3: fc1 + SwiGLU (r2-verified body) + piggybacked w2/b2 conversion ----------------
// r9: (256,3)->(256,4). 4 blocks/CU (LDS 4x32KB=128KB<=160KB); VGPR budget
// 128 (acc 64 + ptrs ~16 + mfma temps ~32 => expected fit, no spill).
// Mechanism: barrier-drain stalls are covered by wave-level TLP (m114);
// +33% resident blocks directly attacks the exposed drain.
__global__ __launch_bounds__(256, 4) void fc1_swiglu_kernel(
    const u16* __restrict__ xb, const u16* __restrict__ w1b, const u16* __restrict__ b1b,
    const float* __restrict__ w2, const float* __restrict__ b2,
    u16* __restrict__ w2b, u16* __restrict__ b2b,
    const u32* __restrict__ counts, const u32* __restrict__ offsets,
    const u16* __restrict__ list, u16* __restrict__ a_packed)
{
    const int tid = threadIdx.x;
    const int bid = (int)blockIdx.x;

    if (bid >= FC1_BLOCKS) {
        const size_t i = ((size_t)(bid - FC1_BLOCKS) * 256 + tid) * 8;
        if (i < W2N) convert8(w2, w2b, i);
        else         convert8(b2, b2b, i - W2N);
        return;
    }

    const int e   = bid & 7;            // XCD pin (round-robin bid%8)
    const int idx = bid >> 3;
    const int n0   = (idx & 15) * 64;   // x fastest: A-panel reuse on-XCD
    const int row0 = (idx >> 4) * 128;
    const int cnt = (int)counts[e];
    if (row0 >= cnt) return;

    __shared__ u16 As[128 * 64], B1s[64 * 64], B2s[64 * 64];

    const int wave = tid >> 6, lane = tid & 63;
    const int mrow0 = (wave >> 1) * 64;
    const int ncol0 = (wave & 1) * 32;
    const int mm = lane & 15;
    const int qb = lane >> 4;
    const int msw = mm & 7;

    const u16 *srcA[4], *srcB1[2], *srcB2[2];
    u16 *dstA[4], *dstB1[2], *dstB2[2];
    const int lrow8 = lane >> 3;
    const int colOff = ((lane & 7) ^ lrow8) << 3;   // element offset (bf16)
#pragma unroll
    for (int j = 0; j < 4; j++) {               // A: 32 rows per wave
        int r = row0 + wave * 32 + j * 8 + lrow8;
        if (r >= cnt) r = cnt - 1;
        const int tok = (int)(list[e * NTOK + r] & 0xFFFu);
        srcA[j] = xb + (size_t)tok * DDIM + colOff;
        dstA[j] = &As[(wave * 32 + j * 8) * 64];
    }
#pragma unroll
    for (int j = 0; j < 2; j++) {               // B1/B2: 16 rows per wave
        const int n = n0 + wave * 16 + j * 8 + lrow8;
        srcB1[j] = w1b + ((size_t)e * 2 * HDIM + n) * DDIM + colOff;
        srcB2[j] = w1b + ((size_t)e * 2 * HDIM + HDIM + n) * DDIM + colOff;
        dstB1[j] = &B1s[(wave * 16 + j * 8) * 64];
        dstB2[j] = &B2s[(wave * 16 + j * 8) * 64];
    }

    f32x4 acc1[4][2], acc2[4][2];
#pragma unroll
    for (int mt = 0; mt < 4; mt++)
#pragma unroll
        for (int nt = 0; nt < 2; nt++) {
            acc1[mt][nt] = f32x4{0, 0, 0, 0};
            acc2[mt][nt] = f32x4{0, 0, 0, 0};
        }

    for (int k0 = 0; k0 < DDIM; k0 += 64) {
        __syncthreads();
#pragma unroll
        for (int j = 0; j < 4; j++) gl16(srcA[j] + k0, dstA[j]);
#pragma unroll
        for (int j = 0; j < 2; j++) gl16(srcB1[j] + k0, dstB1[j]);
#pragma unroll
        for (int j = 0; j < 2; j++) gl16(srcB2[j] + k0, dstB2[j]);
        __syncthreads();   // drains vmcnt(0) before s_barrier
#pragma unroll
        for (int kk = 0; kk < 2; kk++) {
            const int g = kk * 4 + qb;
            bf16x8 af[4];
#pragma unroll
            for (int mt = 0; mt < 4; mt++)
                af[mt] = *(const bf16x8*)(&As[(mrow0 + mt * 16 + mm) * 64 + ((g ^ msw) << 3)]);
#pragma unroll
            for (int nt = 0; nt < 2; nt++) {
                const bf16x8 b1f = *(const bf16x8*)(&B1s[(ncol0 + nt * 16 + mm) * 64 + ((g ^ msw) << 3)]);
                const bf16x8 b2f = *(const bf16x8*)(&B2s[(ncol0 + nt * 16 + mm) * 64 + ((g ^ msw) << 3)]);
#pragma unroll
                for (int mt = 0; mt < 4; mt++) {
                    acc1[mt][nt] = __builtin_amdgcn_mfma_f32_16x16x32_bf16(af[mt], b1f, acc1[mt][nt], 0, 0, 0);
                    acc2[mt][nt] = __builtin_amdgcn_mfma_f32_16x16x32_bf16(af[mt], b2f, acc2[mt][nt], 0, 0, 0);
                }
            }
        }
    }

    const u32 obase = offsets[e];
    const int rbv = qb * 4;
#pragma unroll
    for (int nt = 0; nt < 2; nt++) {
        const int n = n0 + ncol0 + nt * 16 + mm;
        const float bb1 = b2f(b1b[(size_t)e * 2 * HDIM + n]);
        const float bb2 = b2f(b1b[(size_t)e * 2 * HDIM + HDIM + n]);
#pragma unroll
        for (int mt = 0; mt < 4; mt++) {
#pragma unroll
            for (int r = 0; r < 4; r++) {
                const int gr = row0 + mrow0 + mt * 16 + rbv + r;
                if (gr < cnt) {
                    const float h1 = acc1[mt][nt][r] + bb1;
                    const float h2 = acc2[mt][nt][r] + bb2;
                    const float av = h1 / (1.f + __expf(-h1)) * h2;
                    a_packed[(size_t)(obase + (u32)gr) * HDIM + n] = f2b(av);
                }
            }
        }
    }
}

// ---------------- K4: fc2, 128x64 tile, dbuf prefetch (r5/r7-verified best), slot-direct y write ----------------
__global__ __launch_bounds__(256, 3) void fc2_kernel(
    const u16* __restrict__ a_packed, const u16* __restrict__ w2b, const u16* __restrict__ b2b,
    const u32* __restrict__ counts, const u32* __restrict__ offsets,
    const u16* __restrict__ list, u16* __restrict__ y_tok)
{
    const int tid = threadIdx.x;
    const int bid = (int)blockIdx.x;
    const int e   = bid & 7;            // XCD pin
    const int idx = bid >> 3;
    const int d0   = (idx & 7) * 64;    // x fastest: A-panel reuse on-XCD
    const int row0 = (idx >> 3) * 128;
    const int cnt = (int)counts[e];
    if (row0 >= cnt) return;
    const u32 obase = offsets[e];

    __shared__ u16 As[2 * 128 * 64], Bs[2 * 64 * 64];   // 32KB + 16KB

    const int wave = tid >> 6, lane = tid & 63;
    const int mrow0 = (wave >> 1) * 64;
    const int ncol0 = (wave & 1) * 32;
    const int mm = lane & 15;
    const int qb = lane >> 4;
    const int msw = mm & 7;

    const u16 *srcA[4], *srcB[2];
    int dA[4], dB[2];
    const int lrow8 = lane >> 3;
    const int colOff = ((lane & 7) ^ lrow8) << 3;
#pragma unroll
    for (int j = 0; j < 4; j++) {
        int r = row0 + wave * 32 + j * 8 + lrow8;
        if (r >= cnt) r = cnt - 1;
        srcA[j] = a_packed + (size_t)(obase + (u32)r) * HDIM + colOff;
        dA[j] = (wave * 32 + j * 8) * 64;
    }
#pragma unroll
    for (int j = 0; j < 2; j++) {
        const int d = d0 + wave * 16 + j * 8 + lrow8;
        srcB[j] = w2b + ((size_t)e * DDIM + d) * HDIM + colOff;
        dB[j] = (wave * 16 + j * 8) * 64;
    }

    f32x4 acc[4][2];
#pragma unroll
    for (int mt = 0; mt < 4; mt++)
#pragma unroll
        for (int nt = 0; nt < 2; nt++) acc[mt][nt] = f32x4{0, 0, 0, 0};

    // prologue: stage k0=0 into buffer 0
#pragma unroll
    for (int j = 0; j < 4; j++) gl16(srcA[j], As + dA[j]);
#pragma unroll
    for (int j = 0; j < 2; j++) gl16(srcB[j], Bs + dB[j]);
    __syncthreads();   // vmcnt(0) drain

    int cur = 0;
    for (int k0 = 0; k0 < HDIM; k0 += 64) {
        const int nxt = cur ^ 1;
        if (k0 + 64 < HDIM) {
#pragma unroll
            for (int j = 0; j < 4; j++) gl16(srcA[j] + k0 + 64, As + nxt * 8192 + dA[j]);
#pragma unroll
            for (int j = 0; j < 2; j++) gl16(srcB[j] + k0 + 64, Bs + nxt * 4096 + dB[j]);
        }
        const u16* Ab = As + cur * 8192;
        const u16* Bb = Bs + cur * 4096;
#pragma unroll
        for (int kk = 0; kk < 2; kk++) {
            const int g = kk * 4 + qb;
            bf16x8 af[4];
#pragma unroll
            for (int mt = 0; mt < 4; mt++)
                af[mt] = *(const bf16x8*)(&Ab[(mrow0 + mt * 16 + mm) * 64 + ((g ^ msw) << 3)]);
#pragma unroll
            for (int nt = 0; nt < 2; nt++) {
                const bf16x8 bfv = *(const bf16x8*)(&Bb[(ncol0 + nt * 16 + mm) * 64 + ((g ^ msw) << 3)]);
#pragma unroll
                for (int mt = 0; mt < 4; mt++)
                    acc[mt][nt] = __builtin_amdgcn_mfma_f32_16x16x32_bf16(af[mt], bfv, acc[mt][nt], 0, 0, 0);
            }
        }
        __syncthreads();   // drains vmcnt(0): next-tile stage complete
        cur = nxt;
    }

    const int rbv = qb * 4;
#pragma unroll
    for (int nt = 0; nt < 2; nt++) {
        const int n = d0 + ncol0 + nt * 16 + mm;
        const float bb = b2f(b2b[(size_t)e * DDIM + n]);
#pragma unroll
        for (int mt = 0; mt < 4; mt++) {
#pragma unroll
            for (int r = 0; r < 4; r++) {
                const int gr = row0 + mrow0 + mt * 16 + rbv + r;
                if (gr < cnt) {
                    const u32 v = (u32)list[e * NTOK + gr];
                    const u32 row = ((v & 0xFFFu) << 1) | (v >> 15);   // 2*token + slot
                    y_tok[(size_t)row * DDIM + n] = f2b(acc[mt][nt][r] + bb);
                }
            }
        }
    }
}

// ---------------- K5: weighted combine (pure streaming, no indirection) ----------------
__global__ __launch_bounds__(256) void combine_kernel(
    const u16* __restrict__ y_tok, const float* __restrict__ tok_w,
    float* __restrict__ out)
{
    const int tid = threadIdx.x;
    const int lane = tid & 63;
    const int t = (int)blockIdx.x * 4 + (tid >> 6);
    const float w0 = tok_w[t * 2], w1 = tok_w[t * 2 + 1];

    const uint4 va = *(const uint4*)(y_tok + (size_t)(t * 2)     * DDIM + lane * 8);
    const uint4 vb = *(const uint4*)(y_tok + (size_t)(t * 2 + 1) * DDIM + lane * 8);
    const u16* ap = (const u16*)&va;
    const u16* bp = (const u16*)&vb;
    float r[8];
#pragma unroll
    for (int j = 0; j < 8; j++) r[j] = w0 * b2f(ap[j]) + w1 * b2f(bp[j]);

    float* op = out + (size_t)t * DDIM + lane * 8;
    *(float4*)op       = float4{r[0], r[1], r[2], r[3]};
    *(float4*)(op + 4) = float4{r[4], r[5], r[6], r[7]};
}

extern "C" void kernel_launch(void* const* d_in, const int* in_sizes, int n_in,
                              void* d_out, int out_size, void* d_ws, size_t ws_size,
                              hipStream_t stream)
{
    const float* x  = (const float*)d_in[0];
    const float* rw = (const float*)d_in[1];
    const float* rb = (const float*)d_in[2];
    const float* w1 = (const float*)d_in[3];
    const float* b1 = (const float*)d_in[4];
    const float* w2 = (const float*)d_in[5];
    const float* b2 = (const float*)d_in[6];
    float* outp = (float*)d_out;
    (void)in_sizes; (void)n_in; (void)out_size; (void)ws_size;

    char* ws = (char*)d_ws;
    size_t off = 0;
    auto take = [&](size_t bytes) -> char* {
        char* p = ws + off;
        off = (off + bytes + 255) & ~(size_t)255;
        return p;
    };
    u32* counts    = (u32*)take(NEXP * 4);
    u32* offsets   = (u32*)take(NEXP * 4);
    u16* list      = (u16*)take((size_t)NEXP * NTOK * 2);
    u16* tok_epack = (u16*)take((size_t)NTOK * 2);
    float* tok_w   = (float*)take((size_t)NTOK * 2 * 4);
    u16* a_packed  = (u16*)take((size_t)2 * NTOK * HDIM * 2);   // 16.8 MB
    u16* y_tok     = (u16*)take((size_t)2 * NTOK * DDIM * 2);   // 8.4 MB
    u16* xb  = (u16*)take(XN * 2);                              // 4.2 MB
    u16* w1b = (u16*)take(W1N * 2);                             // 16.8 MB
    u16* b1b = (u16*)take(B1N * 2);
    u16* w2b = (u16*)take(W2N * 2);                             // 8.4 MB
    u16* b2b = (u16*)take(B2N * 2);

    router_conva_kernel<<<ROUTER_BLOCKS + CONVA_BLOCKS, 256, 0, stream>>>(
        x, rw, rb, w1, b1, xb, w1b, b1b, tok_epack, tok_w);

    build_kernel<<<1, 256, 0, stream>>>(tok_epack, counts, offsets, list);

    fc1_swiglu_kernel<<<FC1_BLOCKS + CONVB_BLOCKS, 256, 0, stream>>>(
        xb, w1b, b1b, w2, b2, w2b, b2b, counts, offsets, list, a_packed);

    fc2_kernel<<<FC2_BLOCKS, 256, 0, stream>>>(
        a_packed, w2b, b2b, counts, offsets, list, y_tok);

    combine_kernel<<<NTOK / 4, 256, 0, stream>>>(y_tok, tok_w, outp);
}